// Round 8
// baseline (527.250 us; speedup 1.0000x reference)
//
#include <hip/hip_runtime.h>
#include <hip/hip_bf16.h>

typedef unsigned short u16;
typedef __attribute__((ext_vector_type(8))) short bf16x8;
typedef __attribute__((ext_vector_type(4))) float f32x4;

__device__ __forceinline__ u16 f2b(float f) {
  union { __hip_bfloat16 h; u16 u; } cv;
  cv.h = __float2bfloat16(f);
  return cv.u;
}
__device__ __forceinline__ float b2f(u16 u) {
  union { unsigned int i; float f; } cv;
  cv.i = ((unsigned int)u) << 16;
  return cv.f;
}

// ---------- f32 -> bf16 conversion, 4 elems/thread, exact grid ----------
__global__ void cvt_bf16(const float* __restrict__ in, u16* __restrict__ out) {
  size_t i = ((size_t)blockIdx.x * 256 + threadIdx.x) * 4;
  float4 v = *(const float4*)(in + i);
  ushort4 o;
  o.x = f2b(v.x); o.y = f2b(v.y); o.z = f2b(v.z); o.w = f2b(v.w);
  *(ushort4*)(out + i) = o;
}

// ---------- RoPE cos/sin table: [L=2048][half=32] ----------
__global__ void rope_tab_k(float2* __restrict__ tab) {
  int t = blockIdx.x * 256 + threadIdx.x;   // 65536
  int l = t >> 5, i = t & 31;
  float inv = powf(10000.0f, -(float)i * (1.0f / 32.0f));
  float ang = (float)l * inv;
  tab[t] = make_float2(cosf(ang), sinf(ang));
}

// ---------- reg-pipelined 256x256 GEMM, 4-slot rotation, stage-ahead=4 ----------
// Per phase j: stage(j+4) [slot j&3, dead since reads(j) drained @barrier j-1];
// ds_read frags(j+1) [resident via vmcnt(8)@j-2]; MFMA on pre-loaded frags(j)
// (zero waits); lgkm(0); vmcnt(8); barrier. 2x-unrolled ping-pong frag sets.
template<int NCOLS, bool ROPE>
__global__ __launch_bounds__(512, 2) void gemm_p(const u16* __restrict__ A,
                                                 const u16* __restrict__ Bm,
                                                 const float* __restrict__ bias,
                                                 u16* __restrict__ Cb,
                                                 float* __restrict__ Cf,
                                                 const float2* __restrict__ tab) {
  extern __shared__ char smem[];
  u16* Asl = (u16*)smem;              // 4 slots x 8192 u16 (16KB): [256 rows][32 k]
  u16* Bsl = (u16*)(smem + 65536);
  const int tid = threadIdx.x, lane = tid & 63, w = tid >> 6;
  const int wr = w >> 2, wcn = w & 3;
  const int fr = lane & 15, fk = lane >> 4;
  const int m0 = blockIdx.y * 256, n0 = blockIdx.x * 256;
  const int srow = lane >> 2;                       // staging row within 16-row chunk
  const int gslot = (lane & 3) ^ ((lane >> 3) & 3); // pre-swizzled global 16B slot
  const int c0 = w * 2, c1 = c0 + 1;                // this wave's two chunks
  const int sel = (fr >> 1) & 3;
  const int ka = (fk ^ sel) << 4;                   // swizzled 16B slot on read path
  f32x4 acc[8][4] = {};
  bf16x8 afA[8], bvA[4], afB[8], bvB[4];

  const u16* gA0 = A  + (size_t)(m0 + c0 * 16 + srow) * 2048 + gslot * 8;
  const u16* gA1 = A  + (size_t)(m0 + c1 * 16 + srow) * 2048 + gslot * 8;
  const u16* gB0 = Bm + (size_t)(n0 + c0 * 16 + srow) * 2048 + gslot * 8;
  const u16* gB1 = Bm + (size_t)(n0 + c1 * 16 + srow) * 2048 + gslot * 8;

  auto stage = [&](int jj) {
    int slot = jj & 3;
    int kk = jj * 32;
    u16* Ad = Asl + slot * 8192;
    u16* Bd = Bsl + slot * 8192;
    __builtin_amdgcn_global_load_lds((const __attribute__((address_space(1))) unsigned int*)(gA0 + kk),
        (__attribute__((address_space(3))) unsigned int*)(Ad + c0 * 512), 16, 0, 0);
    __builtin_amdgcn_global_load_lds((const __attribute__((address_space(1))) unsigned int*)(gA1 + kk),
        (__attribute__((address_space(3))) unsigned int*)(Ad + c1 * 512), 16, 0, 0);
    __builtin_amdgcn_global_load_lds((const __attribute__((address_space(1))) unsigned int*)(gB0 + kk),
        (__attribute__((address_space(3))) unsigned int*)(Bd + c0 * 512), 16, 0, 0);
    __builtin_amdgcn_global_load_lds((const __attribute__((address_space(1))) unsigned int*)(gB1 + kk),
        (__attribute__((address_space(3))) unsigned int*)(Bd + c1 * 512), 16, 0, 0);
  };

#define GP_READ(JJ, AF, BV) do {                                              \
    const char* Ab_ = (const char*)(Asl + ((JJ) & 3) * 8192);                 \
    const char* Bb_ = (const char*)(Bsl + ((JJ) & 3) * 8192);                 \
    _Pragma("unroll")                                                         \
    for (int n_ = 0; n_ < 4; ++n_)                                            \
      BV[n_] = *(const bf16x8*)(Bb_ + (wcn * 64 + n_ * 16 + fr) * 64 + ka);   \
    _Pragma("unroll")                                                         \
    for (int m_ = 0; m_ < 8; ++m_)                                            \
      AF[m_] = *(const bf16x8*)(Ab_ + (wr * 128 + m_ * 16 + fr) * 64 + ka);   \
  } while (0)

#define GP_MFMA(AF, BV) do {                                                  \
    __builtin_amdgcn_s_setprio(1);                                            \
    _Pragma("unroll")                                                         \
    for (int m_ = 0; m_ < 8; ++m_)                                            \
      _Pragma("unroll")                                                       \
      for (int n_ = 0; n_ < 4; ++n_)                                          \
        acc[m_][n_] = __builtin_amdgcn_mfma_f32_16x16x32_bf16(AF[m_], BV[n_], acc[m_][n_], 0, 0, 0); \
    __builtin_amdgcn_s_setprio(0);                                            \
  } while (0)

#define GP_VM(P) do {                                                         \
    if ((P) <= 59)      asm volatile("s_waitcnt vmcnt(8)" ::: "memory");      \
    else if ((P) == 60) asm volatile("s_waitcnt vmcnt(4)" ::: "memory");      \
    else                asm volatile("s_waitcnt vmcnt(0)" ::: "memory");      \
  } while (0)

  // prologue: stage slices 0..3, ensure 0,1 resident, pre-load slice-0 frags
  stage(0); stage(1); stage(2); stage(3);
  asm volatile("s_waitcnt vmcnt(8)" ::: "memory");
  asm volatile("s_barrier" ::: "memory");
  GP_READ(0, afA, bvA);
  asm volatile("s_waitcnt lgkmcnt(0)" ::: "memory");
  asm volatile("s_barrier" ::: "memory");

  for (int j = 0; j < 64; j += 2) {
    // ---- phase j: compute slice j (A-set), prefetch slice j+1 (B-set)
    if (j + 4 < 64) stage(j + 4);
    GP_READ(j + 1, afB, bvB);
    __builtin_amdgcn_sched_barrier(0);   // reads issue before MFMA cluster
    GP_MFMA(afA, bvA);
    asm volatile("s_waitcnt lgkmcnt(0)" ::: "memory");
    GP_VM(j);
    asm volatile("s_barrier" ::: "memory");
    // ---- phase j+1: compute slice j+1 (B-set), prefetch slice j+2 (A-set)
    if (j + 5 < 64) stage(j + 5);
    if (j + 2 < 64) GP_READ(j + 2, afA, bvA);
    __builtin_amdgcn_sched_barrier(0);
    GP_MFMA(afB, bvB);
    if (j + 2 < 64) {
      asm volatile("s_waitcnt lgkmcnt(0)" ::: "memory");
      GP_VM(j + 1);
      asm volatile("s_barrier" ::: "memory");
    }
  }
#undef GP_READ
#undef GP_MFMA
#undef GP_VM

  // ---- epilogue: bias (+ fused RoPE for q,k cols when ROPE) ----
  #pragma unroll
  for (int m = 0; m < 8; ++m) {
    int grow0 = m0 + wr * 128 + m * 16 + fk * 4;
    #pragma unroll
    for (int n = 0; n < 4; ++n) {
      int gcol = n0 + wcn * 64 + n * 16 + fr;
      if (ROPE) {
        if (gcol < 4096) {
          int c = gcol & 63;
          int i = c & 31;
          bool lo = c < 32;
          float bx = bias[gcol], bp = bias[gcol ^ 32];
          #pragma unroll
          for (int r = 0; r < 4; ++r) {
            int t = grow0 + r;
            float2 cs = tab[((t & 2047) << 5) + i];
            float xb = acc[m][n][r] + bx;          // this column
            float pb = acc[m][n ^ 2][r] + bp;      // partner column (gcol^32)
            float o = lo ? (xb * cs.x - pb * cs.y) : (pb * cs.y + xb * cs.x);
            Cb[(size_t)t * NCOLS + gcol] = f2b(o);
          }
        } else {
          float bx = bias[gcol];
          #pragma unroll
          for (int r = 0; r < 4; ++r)
            Cb[(size_t)(grow0 + r) * NCOLS + gcol] = f2b(acc[m][n][r] + bx);
        }
      } else {
        float bx = bias[gcol];
        #pragma unroll
        for (int r = 0; r < 4; ++r)
          Cf[(size_t)(grow0 + r) * NCOLS + gcol] = acc[m][n][r] + bx;
      }
    }
  }
}

// ---------- banded attention with sinks ----------
// block = (b, h, n); 4 waves x 16 q-rows. Keys: [0,16)=sinks, [16,208)=band, [208,224)=pad
// Vt layout: [64 dout][32 granule slots of 8 keys], granule gi stored at slot
// gi ^ (dout&7) (slots 24..31 are swizzle images of group-3 granules), row 512B.
#define PSTR 232
__global__ __launch_bounds__(256) void attn_k(const u16* __restrict__ qkv,
                                              const float* __restrict__ sinks,
                                              u16* __restrict__ O) {
  extern __shared__ char smem[];          // 66816 B
  char* Kraw = smem;                      // phase 1: K_all [224][64] bf16, XOR-swizzled
  char* Qraw = smem + 28672;              // phase 1: Q [64][64] bf16, XOR-swizzled
  u16* Ps = (u16*)smem;                   // phase 3: P [64][PSTR]            (29696 B)
  u16* Vt = (u16*)(smem + 29696);         // phase 3: V^T [64][256] swizzled  (32768 B)
  char* tmpb = smem + 62464;              // phase 3: 4 waves x 1088B transpose tile
  const int tid = threadIdx.x, lane = tid & 63, wid = tid >> 6;
  const int fr = lane & 15, fk = lane >> 4;
  const int bx = blockIdx.x;
  const int n = bx & 31, h = (bx >> 5) & 31, b = bx >> 10;
  const size_t qrow0 = (size_t)b * 2048 + n * 64;

  // ---- phase 1: stage Q and K_all
  for (int c = tid; c < 512; c += 256) {          // Q: 64 rows x 128B
    int row = c >> 3, colb = (c & 7) * 16;
    uint4 v = *(const uint4*)((const char*)(qkv + (qrow0 + row) * 6144 + h * 64) + colb);
    *(uint4*)(Qraw + ((row * 128 + colb) ^ ((row & 7) << 4))) = v;
  }
  {                                               // sinks -> K rows 0..15 (fp32->bf16)
    int row = tid >> 4, col4 = (tid & 15) * 4;
    float4 v = *(const float4*)(sinks + ((size_t)h * 16 + row) * 64 + col4);
    ushort4 o; o.x = f2b(v.x); o.y = f2b(v.y); o.z = f2b(v.z); o.w = f2b(v.w);
    *(ushort4*)(Kraw + ((row * 128 + col4 * 2) ^ ((row & 7) << 4))) = o;
  }
  for (int c = tid; c < 1536; c += 256) {         // band K -> rows 16..207
    int kidx = c >> 3, colb = (c & 7) * 16;
    int blk = n - 1 + (kidx >> 6);
    int blkc = min(max(blk, 0), 31);
    int kpos = blkc * 64 + (kidx & 63);
    uint4 v = *(const uint4*)((const char*)(qkv + ((size_t)b * 2048 + kpos) * 6144 + 2048 + h * 64) + colb);
    int row = 16 + kidx;
    *(uint4*)(Kraw + ((row * 128 + colb) ^ ((row & 7) << 4))) = v;
  }
  if (tid < 128) {                                // zero pad rows 208..223
    int row = 208 + (tid >> 3), colb = (tid & 7) * 16;
    uint4 z = {0, 0, 0, 0};
    *(uint4*)(Kraw + ((row * 128 + colb) ^ ((row & 7) << 4))) = z;
  }
  __syncthreads();

  // ---- phase 2: QK^T (MFMA) + masked softmax in registers
  bf16x8 qf[2];
  {
    int qrow = wid * 16 + fr;
    #pragma unroll
    for (int kc = 0; kc < 2; ++kc)
      qf[kc] = *(const bf16x8*)(Qraw + ((qrow * 128 + kc * 64 + fk * 16) ^ ((qrow & 7) << 4)));
  }
  f32x4 sacc[14];
  #pragma unroll
  for (int g = 0; g < 14; ++g) {
    int key = g * 16 + fr;
    bf16x8 kf0 = *(const bf16x8*)(Kraw + ((key * 128 + fk * 16) ^ ((key & 7) << 4)));
    bf16x8 kf1 = *(const bf16x8*)(Kraw + ((key * 128 + 64 + fk * 16) ^ ((key & 7) << 4)));
    f32x4 a = {};
    a = __builtin_amdgcn_mfma_f32_16x16x32_bf16(qf[0], kf0, a, 0, 0, 0);
    a = __builtin_amdgcn_mfma_f32_16x16x32_bf16(qf[1], kf1, a, 0, 0, 0);
    sacc[g] = a;
  }
  float rowmax[4] = {-3e38f, -3e38f, -3e38f, -3e38f};
  #pragma unroll
  for (int g = 0; g < 14; ++g) {
    int key = g * 16 + fr;
    #pragma unroll
    for (int r = 0; r < 4; ++r) {
      float s = sacc[g][r] * 0.125f;
      bool valid;
      if (key < 16) valid = true;
      else if (key < 208) {
        int kidx = key - 16;
        int blk = n - 1 + (kidx >> 6);
        int kpos = blk * 64 + (kidx & 63);
        int qpos = n * 64 + wid * 16 + fk * 4 + r;
        valid = (blk >= 0) && (blk < 32) && (qpos - kpos <= 64) && (kpos - qpos <= 64);
      } else valid = false;
      s = valid ? s : -1e30f;
      sacc[g][r] = s;
      rowmax[r] = fmaxf(rowmax[r], s);
    }
  }
  #pragma unroll
  for (int d = 1; d < 16; d <<= 1)
    #pragma unroll
    for (int r = 0; r < 4; ++r)
      rowmax[r] = fmaxf(rowmax[r], __shfl_xor(rowmax[r], d));
  float rowsum[4] = {0, 0, 0, 0};
  #pragma unroll
  for (int g = 0; g < 14; ++g)
    #pragma unroll
    for (int r = 0; r < 4; ++r) {
      float p = __expf(sacc[g][r] - rowmax[r]);
      sacc[g][r] = p;
      rowsum[r] += p;
    }
  #pragma unroll
  for (int d = 1; d < 16; d <<= 1)
    #pragma unroll
    for (int r = 0; r < 4; ++r)
      rowsum[r] += __shfl_xor(rowsum[r], d);
  __syncthreads();   // Kall/Q now dead; Ps/Vt/tmp regions become writable

  // ---- phase 3: write unnormalized P (bf16); stage V via coalesced load +
  //      per-wave LDS transpose tile -> packed b128 writes into swizzled Vt.
  #pragma unroll
  for (int g = 0; g < 14; ++g)
    #pragma unroll
    for (int r = 0; r < 4; ++r)
      Ps[(wid * 16 + fk * 4 + r) * PSTR + g * 16 + fr] = f2b(sacc[g][r]);

  {
    u16* tw = (u16*)(tmpb + wid * 1088);  // per-wave [8 keys][68 u16] (136B rows)
    const int g = lane >> 3, s = lane & 7; // key sub-idx, dout-group
    // sinks (granules 0,1 by waves 0,1) + zero-pad (granules 26,27 by waves 2,3)
    if (wid < 2) {
      int key = wid * 8 + g;
      float4 v0 = *(const float4*)(sinks + ((size_t)h * 16 + key) * 64 + s * 8);
      float4 v1 = *(const float4*)(sinks + ((size_t)h * 16 + key) * 64 + s * 8 + 4);
      u16* dst = tw + g * 68 + s * 8;
      dst[0] = f2b(v0.x); dst[1] = f2b(v0.y); dst[2] = f2b(v0.z); dst[3] = f2b(v0.w);
      dst[4] = f2b(v1.x); dst[5] = f2b(v1.y); dst[6] = f2b(v1.z); dst[7] = f2b(v1.w);
      u16 col[8];
      #pragma unroll
      for (int k = 0; k < 8; ++k) col[k] = tw[k * 68 + lane];
      *(bf16x8*)(Vt + lane * 256 + ((wid ^ (lane & 7)) * 8)) = *(bf16x8*)col;
    } else {
      bf16x8 z = {};
      *(bf16x8*)(Vt + lane * 256 + (((24 + wid) ^ (lane & 7)) * 8)) = z;  // 26,27
    }
    // band V: 6 iters x (wave covers 8 keys x 64 dout)
    for (int it = 0; it < 6; ++it) {
      int kidx = it * 32 + wid * 8 + g;          // 0..191
      int blk = n - 1 + (kidx >> 6);
      int blkc = min(max(blk, 0), 31);
      int kpos = blkc * 64 + (kidx & 63);
      uint4 v = *(const uint4*)(qkv + ((size_t)b * 2048 + kpos) * 6144 + 4096 + h * 64 + s * 8);
      *(uint4*)(tw + g * 68 + s * 8) = v;
      u16 col[8];
      #pragma unroll
      for (int k = 0; k < 8; ++k) col[k] = tw[k * 68 + lane];
      int gi = 2 + it * 4 + wid;                 // granule 2..25
      *(bf16x8*)(Vt + lane * 256 + ((gi ^ (lane & 7)) * 8)) = *(bf16x8*)col;
    }
  }
  __syncthreads();

  // ---- phase 4: O = P * V  (B-frag from swizzled Vt granules)
  f32x4 oacc[4] = {};
  #pragma unroll
  for (int kc = 0; kc < 7; ++kc) {
    bf16x8 pf = *(const bf16x8*)(Ps + (wid * 16 + fr) * PSTR + kc * 32 + fk * 8);
    #pragma unroll
    for (int gd = 0; gd < 4; ++gd) {
      bf16x8 vf = *(const bf16x8*)(Vt + (gd * 16 + fr) * 256 + (((kc * 4 + fk) ^ (fr & 7)) * 8));
      oacc[gd] = __builtin_amdgcn_mfma_f32_16x16x32_bf16(pf, vf, oacc[gd], 0, 0, 0);
    }
  }
  #pragma unroll
  for (int gd = 0; gd < 4; ++gd)
    #pragma unroll
    for (int r = 0; r < 4; ++r) {
      int qrl = wid * 16 + fk * 4 + r;
      float v = oacc[gd][r] / rowsum[r];
      O[(qrow0 + qrl) * 2048 + h * 64 + gd * 16 + fr] = f2b(v);
    }
}

extern "C" void kernel_launch(void* const* d_in, const int* in_sizes, int n_in,
                              void* d_out, int out_size, void* d_ws, size_t ws_size,
                              hipStream_t stream) {
  const float* u     = (const float*)d_in[0];
  const float* Wqkv  = (const float*)d_in[1];
  const float* bqkv  = (const float*)d_in[2];
  const float* Wo    = (const float*)d_in[3];
  const float* bo    = (const float*)d_in[4];
  const float* sinks = (const float*)d_in[5];
  float* out = (float*)d_out;

  char* ws = (char*)d_ws;
  u16* u_bf   = (u16*)ws;                      // 33,554,432 B  (reused as O_bf)
  u16* w1_bf  = (u16*)(ws + 33554432);         // 25,165,824 B  (reused for Wo)
  u16* qkv_bf = (u16*)(ws + 58720256);         // 100,663,296 B
  float2* tab = (float2*)(ws + 159383552);     //     524,288 B
  u16* O_bf  = u_bf;
  u16* w2_bf = w1_bf;

  hipFuncSetAttribute((const void*)gemm_p<6144, true>,
                      hipFuncAttributeMaxDynamicSharedMemorySize, 131072);
  hipFuncSetAttribute((const void*)gemm_p<2048, false>,
                      hipFuncAttributeMaxDynamicSharedMemorySize, 131072);
  hipFuncSetAttribute((const void*)attn_k,
                      hipFuncAttributeMaxDynamicSharedMemorySize, 66816);

  cvt_bf16<<<16384, 256, 0, stream>>>(u, u_bf);          // 16.7M elems
  cvt_bf16<<<12288, 256, 0, stream>>>(Wqkv, w1_bf);      // 12.6M elems
  rope_tab_k<<<256, 256, 0, stream>>>(tab);
  gemm_p<6144, true><<<dim3(24, 32), 512, 131072, stream>>>(u_bf, w1_bf, bqkv, qkv_bf, nullptr, tab);
  attn_k<<<4096, 256, 66816, stream>>>(qkv_bf, sinks, O_bf);
  cvt_bf16<<<4096, 256, 0, stream>>>(Wo, w2_bf);         // 4.2M elems
  gemm_p<2048, false><<<dim3(8, 32), 512, 131072, stream>>>(O_bf, w2_bf, bo, nullptr, out, nullptr);
}